// Round 10
// baseline (102.774 us; speedup 1.0000x reference)
//
#include <hip/hip_runtime.h>
#include <hip/hip_bf16.h>

#define B_SENT 128
#define L_TOK  256
#define D_DIM  1024
#define TM     64              // tokens per block
#define TN     64              // sentences per block (B split in 2)
#define BK     32              // K per step == MFMA K
#define NKB    (D_DIM / BK)    // 32 K-steps
#define NBUF   4               // LDS buffers; 3 stages in flight

typedef __attribute__((ext_vector_type(8))) short bf16x8;
typedef __attribute__((ext_vector_type(4))) float f32x4;

__device__ __forceinline__ unsigned short f2bf(float f) {
    return __builtin_bit_cast(unsigned short, __float2bfloat16(f));
}
__device__ __forceinline__ float softplus_f(float x) {
    float ax = fabsf(x);
    return fmaxf(x, 0.0f) + __logf(1.0f + __expf(-ax));
}
__device__ __forceinline__ bf16x8 cvt8f(const f32x4& lo, const f32x4& hi) {
    bf16x8 u;
    u[0] = (short)f2bf(lo[0]); u[1] = (short)f2bf(lo[1]);
    u[2] = (short)f2bf(lo[2]); u[3] = (short)f2bf(lo[3]);
    u[4] = (short)f2bf(hi[0]); u[5] = (short)f2bf(hi[1]);
    u[6] = (short)f2bf(hi[2]); u[7] = (short)f2bf(hi[3]);
    return u;
}

// async global->LDS, 16 B per lane. LDS base wave-uniform; global src per-lane.
__device__ __forceinline__ void gl_lds16(const void* g, void* l) {
    __builtin_amdgcn_global_load_lds(
        (const __attribute__((address_space(1))) unsigned int*)g,
        (__attribute__((address_space(3))) unsigned int*)l, 16, 0, 0);
}

// ---------------------------------------------------------------------------
// Pre-pack glob (f32) -> bf16 MFMA B-fragments, BK=32 chunks (512 KB total):
// packed[[side][kb][n][lane][e]] = glob[side][n*16+(lane&15)][kb*32+(lane>>4)*8+e]
// ---------------------------------------------------------------------------
__global__ __launch_bounds__(256) void pack_g_kernel(
    const float* __restrict__ g0, const float* __restrict__ g1,
    short* __restrict__ packed)
{
    const int idx  = blockIdx.x * 256 + threadIdx.x;   // 0..32767
    const int lane = idx & 63;
    const int n    = (idx >> 6) & 7;
    const int kb   = (idx >> 9) & 31;
    const int side = idx >> 14;
    const int row  = n * 16 + (lane & 15);
    const int col  = kb * 32 + (lane >> 4) * 8;
    const float* g = side ? g1 : g0;
    const f32x4 v0 = *reinterpret_cast<const f32x4*>(&g[(size_t)row * D_DIM + col]);
    const f32x4 v1 = *reinterpret_cast<const f32x4*>(&g[(size_t)row * D_DIM + col + 4]);
    *reinterpret_cast<bf16x8*>(&packed[(size_t)idx * 8]) = cvt8f(v0, v1);
}

// ---------------------------------------------------------------------------
// Main: all-gl_lds counted-vmcnt pipeline (round-6 protocol, deepened).
// Block = 64 tokens x 64 sentences, 4 waves (16 token rows each).
// Per stage per wave: exactly 3 gl_lds (2 A + 1 B). 4 buffers, 3 stages in
// flight; steady wait = vmcnt(6) -> 2 full K-steps of latency slack.
// ---------------------------------------------------------------------------
__global__ __launch_bounds__(256, 4) void mi_main_kernel(
    const float* __restrict__ tok0, const float* __restrict__ tok1,
    const int* __restrict__ len0, const int* __restrict__ len1,
    const short* __restrict__ packed, float* __restrict__ acc_ws)
{
    const int side = blockIdx.y;
    const float* tok = side ? tok1 : tok0;
    const int*   len = side ? len1 : len0;

    const int bx     = blockIdx.x;       // 0..1023
    const int tile   = bx >> 1;          // 0..511 token tile
    const int nh     = bx & 1;           // sentence half
    const int b_sent = tile >> 2;        // 4 token tiles per sentence
    const int tb     = b_sent * L_TOK + (tile & 3) * TM;
    const int count  = max(1, len[b_sent]) - (tile & 3) * TM;
    if (count <= 0) return;              // uniform whole-block exit

    const int tid  = threadIdx.x;
    const int wave = tid >> 6;           // 0..3
    const int lane = tid & 63;
    const int lrow = lane & 15;
    const int kgrp = lane >> 4;

    __shared__ float As[NBUF][2048];     // 8 KB/buf: 8 regions x 64 lanes x 16 B
    __shared__ short Bs[NBUF][2048];     // 4 KB/buf: 4 regions x 64 lanes x 16 B
    __shared__ float sred[8];

    // A source: row clamped to count-1 (dup fetches hit cache; garbage rows
    // are skipped by the epilogue mask).
    const int arow = min(wave * 16 + lrow, count - 1);
    const float* asrc = tok + (size_t)(tb + arow) * D_DIM + kgrp * 8;
    // B source: this block's 4 fragment regions are n = nh*4 .. nh*4+3;
    // wave w stages region w.
    const short* bchunk = packed + (size_t)side * NKB * 4096;
    const int boff = ((nh * 4 + wave) * 64 + lane) * 8;

    f32x4 acc[4];
#pragma unroll
    for (int n = 0; n < 4; ++n) acc[n] = (f32x4){0.f, 0.f, 0.f, 0.f};

    auto stage = [&](int buf, int kb) {            // exactly 3 gl_lds
        const float* a = asrc + kb * BK;
        gl_lds16(a,     &As[buf][(wave * 2 + 0) * 256]);
        gl_lds16(a + 4, &As[buf][(wave * 2 + 1) * 256]);
        gl_lds16(bchunk + (size_t)kb * 4096 + boff, &Bs[buf][wave * 512]);
    };

    auto compute = [&](int buf) {
        const f32x4 alo = *reinterpret_cast<const f32x4*>(
            &As[buf][(wave * 2 + 0) * 256 + lane * 4]);
        const f32x4 ahi = *reinterpret_cast<const f32x4*>(
            &As[buf][(wave * 2 + 1) * 256 + lane * 4]);
        const bf16x8 af = cvt8f(alo, ahi);
#pragma unroll
        for (int n = 0; n < 4; ++n) {
            bf16x8 b = *reinterpret_cast<const bf16x8*>(&Bs[buf][(n * 64 + lane) * 8]);
            acc[n] = __builtin_amdgcn_mfma_f32_16x16x32_bf16(af, b, acc[n], 0, 0, 0);
        }
    };

#define WAITSTEP(N) do {                                                     \
        asm volatile("s_waitcnt vmcnt(" #N ")" ::: "memory");                \
        __builtin_amdgcn_s_barrier();                                        \
        __builtin_amdgcn_sched_barrier(0);                                   \
    } while (0)

    // prologue: 3 stages in flight (9 VMEM ops)
    stage(0, 0);
    stage(1, 1);
    stage(2, 2);
#pragma unroll 1
    for (int kb = 0; kb < NKB - 3; ++kb) {   // kb = 0..28
        WAITSTEP(6);                         // stage kb landed (9 -> 6)
        stage((kb + 3) & 3, kb + 3);         // stages 3..31
        compute(kb & 3);
    }
    WAITSTEP(6); compute((NKB - 3) & 3);     // kb = 29
    WAITSTEP(3); compute((NKB - 2) & 3);     // kb = 30
    WAITSTEP(0); compute((NKB - 1) & 3);     // kb = 31
#undef WAITSTEP

    // ---- epilogue: masked softplus reduction ----
    // C/D layout: col = lane&15 (sentence within frag), row = kgrp*4 + j
    float ep = 0.f, en = 0.f;
#pragma unroll
    for (int n = 0; n < 4; ++n) {
        const int g = nh * TN + n * 16 + lrow;     // global sentence id
#pragma unroll
        for (int j = 0; j < 4; ++j) {
            const int rl = wave * 16 + kgrp * 4 + j;   // local token row
            if (rl < count) {
                float res = acc[n][j];
                float sp  = softplus_f(res);
                if (g == b_sent) ep += res - sp;   // -softplus(-res)
                else             en += sp;         // softplus(-res)+res
            }
        }
    }

#pragma unroll
    for (int off = 32; off; off >>= 1) {
        ep += __shfl_down(ep, off);
        en += __shfl_down(en, off);
    }
    if (lane == 0) { sred[wave * 2] = ep; sred[wave * 2 + 1] = en; }
    __syncthreads();
    if (tid == 0) {
        float tep = sred[0] + sred[2] + sred[4] + sred[6];
        float ten = sred[1] + sred[3] + sred[5] + sred[7];
        atomicAdd(&acc_ws[side * 2 + 0], tep);
        atomicAdd(&acc_ws[side * 2 + 1], ten);
    }
}

__global__ void mi_finalize_kernel(const int* __restrict__ len0,
                                   const int* __restrict__ len1,
                                   const float* __restrict__ acc_ws,
                                   float* __restrict__ out)
{
    const int lane = threadIdx.x;   // 1 wave
    int s0 = 0, s1 = 0;
    for (int i = lane; i < B_SENT; i += 64) {
        s0 += max(1, len0[i]);
        s1 += max(1, len1[i]);
    }
#pragma unroll
    for (int off = 32; off; off >>= 1) {
        s0 += __shfl_down(s0, off);
        s1 += __shfl_down(s1, off);
    }
    if (lane == 0) {
        const float num_nodes = (float)(s0 + s1);
        const float ep = acc_ws[0] + acc_ws[2];
        const float en = acc_ws[1] + acc_ws[3];
        out[0] = en / (num_nodes * (float)(B_SENT - 1)) - ep / num_nodes;
        out[1] = ((float)s0 + (float)s1) / (2.0f * (float)B_SENT);
    }
}

extern "C" void kernel_launch(void* const* d_in, const int* in_sizes, int n_in,
                              void* d_out, int out_size, void* d_ws, size_t ws_size,
                              hipStream_t stream) {
    const float* tok0  = (const float*)d_in[0];
    const float* tok1  = (const float*)d_in[1];
    const float* glob0 = (const float*)d_in[2];
    const float* glob1 = (const float*)d_in[3];
    const int*   len0  = (const int*)d_in[4];
    const int*   len1  = (const int*)d_in[5];
    float* out = (float*)d_out;

    float* acc    = (float*)d_ws;                       // 4 floats @ offset 0
    short* packed = (short*)((char*)d_ws + 256);        // 512 KB bf16 fragments

    hipMemsetAsync(d_ws, 0, 256, stream);
    pack_g_kernel<<<128, 256, 0, stream>>>(glob0, glob1, packed);

    dim3 grid(1024, 2);   // (512 token-tiles x 2 sentence-halves) x 2 sides
    mi_main_kernel<<<grid, 256, 0, stream>>>(tok0, tok1, len0, len1, packed, acc);
    mi_finalize_kernel<<<1, 64, 0, stream>>>(len0, len1, acc, out);
}

// Round 11
// 92.943 us; speedup vs baseline: 1.1058x; 1.1058x over previous
//
#include <hip/hip_runtime.h>
#include <hip/hip_bf16.h>

#define B_SENT 128
#define L_TOK  256
#define D_DIM  1024
#define TM     32              // tokens per block (8 tiles per sentence)
#define BK     32              // K per step == MFMA K
#define NKB    (D_DIM / BK)    // 32 K-steps
#define NBUF   4               // LDS buffers; 3 stages in flight, slack 2

typedef __attribute__((ext_vector_type(8))) short bf16x8;
typedef __attribute__((ext_vector_type(4))) float f32x4;

__device__ __forceinline__ unsigned short f2bf(float f) {
    return __builtin_bit_cast(unsigned short, __float2bfloat16(f));
}
__device__ __forceinline__ float softplus_f(float x) {
    float ax = fabsf(x);
    return fmaxf(x, 0.0f) + __logf(1.0f + __expf(-ax));
}
__device__ __forceinline__ bf16x8 cvt8f(const f32x4& lo, const f32x4& hi) {
    bf16x8 u;
    u[0] = (short)f2bf(lo[0]); u[1] = (short)f2bf(lo[1]);
    u[2] = (short)f2bf(lo[2]); u[3] = (short)f2bf(lo[3]);
    u[4] = (short)f2bf(hi[0]); u[5] = (short)f2bf(hi[1]);
    u[6] = (short)f2bf(hi[2]); u[7] = (short)f2bf(hi[3]);
    return u;
}

// async global->LDS, 16 B per lane. LDS base wave-uniform; global src per-lane.
__device__ __forceinline__ void gl_lds16(const void* g, void* l) {
    __builtin_amdgcn_global_load_lds(
        (const __attribute__((address_space(1))) unsigned int*)g,
        (__attribute__((address_space(3))) unsigned int*)l, 16, 0, 0);
}

// ---------------------------------------------------------------------------
// Pre-pack glob (f32) -> bf16 MFMA B-fragments, BK=32 chunks (512 KB total):
// packed[[side][kb][n][lane][e]] = glob[side][n*16+(lane&15)][kb*32+(lane>>4)*8+e]
// ---------------------------------------------------------------------------
__global__ __launch_bounds__(256) void pack_g_kernel(
    const float* __restrict__ g0, const float* __restrict__ g1,
    short* __restrict__ packed)
{
    const int idx  = blockIdx.x * 256 + threadIdx.x;   // 0..32767
    const int lane = idx & 63;
    const int n    = (idx >> 6) & 7;
    const int kb   = (idx >> 9) & 31;
    const int side = idx >> 14;
    const int row  = n * 16 + (lane & 15);
    const int col  = kb * 32 + (lane >> 4) * 8;
    const float* g = side ? g1 : g0;
    const f32x4 v0 = *reinterpret_cast<const f32x4*>(&g[(size_t)row * D_DIM + col]);
    const f32x4 v1 = *reinterpret_cast<const f32x4*>(&g[(size_t)row * D_DIM + col + 4]);
    *reinterpret_cast<bf16x8*>(&packed[(size_t)idx * 8]) = cvt8f(v0, v1);
}

// ---------------------------------------------------------------------------
// Main: R10 protocol (all-gl_lds, counted vmcnt, NBUF=4, slack 2) with
// single-A-traffic geometry. Block = 32 tokens x 128 sentences, 4 waves;
// wave w: token half wh=w&1 (16 rows), sentence half nh2=w>>1 (64 cols).
// Per stage per wave: exactly 3 gl_lds (1 A region + 2 B regions).
// A LDS regions lane-major: region r = wh + ch*2 holds rows (r&1)*16+(l&15),
// cols kb*32 + (l>>4)*8 + (r>>1)*4 .. +4 at float offset r*256 + l*4.
// ---------------------------------------------------------------------------
__global__ __launch_bounds__(256, 4) void mi_main_kernel(
    const float* __restrict__ tok0, const float* __restrict__ tok1,
    const int* __restrict__ len0, const int* __restrict__ len1,
    const short* __restrict__ packed, float* __restrict__ acc_ws)
{
    const int side = blockIdx.y;
    const float* tok = side ? tok1 : tok0;
    const int*   len = side ? len1 : len0;

    const int tile   = blockIdx.x;       // 0..1023
    const int b_sent = tile >> 3;        // 8 tiles per sentence
    const int tb     = b_sent * L_TOK + (tile & 7) * TM;
    const int count  = max(1, len[b_sent]) - (tile & 7) * TM;
    if (count <= 0) return;              // uniform whole-block exit

    const int tid  = threadIdx.x;
    const int wave = tid >> 6;           // 0..3
    const int lane = tid & 63;
    const int lrow = lane & 15;
    const int kgrp = lane >> 4;
    const int wh   = wave & 1;           // token half (16 rows)
    const int nh2  = wave >> 1;          // sentence half (64 cols)

    __shared__ float As[NBUF][1024];     // 4 KB/buf: 4 regions x 64 lanes x 16 B
    __shared__ short Bs[NBUF][4096];     // 8 KB/buf: 8 regions x 64 lanes x 16 B
    __shared__ float sred[8];

    // --- staging sources (wave w stages A region w, B regions 2w, 2w+1) ---
    // A region w: row (w&1)*16 + (l&15) clamped, cols (l>>4)*8 + (w>>1)*4
    const int srow = min((wave & 1) * 16 + lrow, count - 1);
    const float* asrc = tok + (size_t)(tb + srow) * D_DIM
                        + kgrp * 8 + (wave >> 1) * 4;
    const short* bchunk = packed + (size_t)side * NKB * 4096;
    const int boff0 = ((wave * 2 + 0) * 64 + lane) * 8;
    const int boff1 = ((wave * 2 + 1) * 64 + lane) * 8;

    f32x4 acc[4];
#pragma unroll
    for (int n = 0; n < 4; ++n) acc[n] = (f32x4){0.f, 0.f, 0.f, 0.f};

    auto stage = [&](int buf, int kb) {            // exactly 3 gl_lds, fixed order
        gl_lds16(asrc + kb * BK, &As[buf][wave * 256]);
        const short* bc = bchunk + (size_t)kb * 4096;
        gl_lds16(bc + boff0, &Bs[buf][(wave * 2 + 0) * 512]);
        gl_lds16(bc + boff1, &Bs[buf][(wave * 2 + 1) * 512]);
    };

    auto compute = [&](int buf) {
        const f32x4 alo = *reinterpret_cast<const f32x4*>(
            &As[buf][(wh + 0) * 256 + lane * 4]);      // cols (l>>4)*8 + 0..3
        const f32x4 ahi = *reinterpret_cast<const f32x4*>(
            &As[buf][(wh + 2) * 256 + lane * 4]);      // cols (l>>4)*8 + 4..7
        const bf16x8 af = cvt8f(alo, ahi);
#pragma unroll
        for (int n = 0; n < 4; ++n) {
            bf16x8 b = *reinterpret_cast<const bf16x8*>(
                &Bs[buf][((nh2 * 4 + n) * 64 + lane) * 8]);
            acc[n] = __builtin_amdgcn_mfma_f32_16x16x32_bf16(af, b, acc[n], 0, 0, 0);
        }
    };

#define WAITSTEP(N) do {                                                     \
        asm volatile("s_waitcnt vmcnt(" #N ")" ::: "memory");                \
        __builtin_amdgcn_s_barrier();                                        \
        __builtin_amdgcn_sched_barrier(0);                                   \
    } while (0)

    // prologue: 3 stages in flight (9 VMEM ops/wave)
    stage(0, 0);
    stage(1, 1);
    stage(2, 2);
#pragma unroll 1
    for (int kb = 0; kb < NKB - 3; ++kb) {   // kb = 0..28, issues stages 3..31
        WAITSTEP(6);                         // stage kb landed (9 -> 6)
        stage((kb + 3) & 3, kb + 3);
        compute(kb & 3);
    }
    WAITSTEP(6); compute((NKB - 3) & 3);     // kb = 29
    WAITSTEP(3); compute((NKB - 2) & 3);     // kb = 30
    WAITSTEP(0); compute((NKB - 1) & 3);     // kb = 31
#undef WAITSTEP

    // ---- epilogue: masked softplus reduction ----
    // C/D layout: col = lane&15 (sentence within frag), row = kgrp*4 + j
    float ep = 0.f, en = 0.f;
#pragma unroll
    for (int n = 0; n < 4; ++n) {
        const int g = nh2 * 64 + n * 16 + lrow;        // global sentence id
#pragma unroll
        for (int j = 0; j < 4; ++j) {
            const int rl = wh * 16 + kgrp * 4 + j;     // local token row
            if (rl < count) {
                float res = acc[n][j];
                float sp  = softplus_f(res);
                if (g == b_sent) ep += res - sp;   // -softplus(-res)
                else             en += sp;         // softplus(-res)+res
            }
        }
    }

#pragma unroll
    for (int off = 32; off; off >>= 1) {
        ep += __shfl_down(ep, off);
        en += __shfl_down(en, off);
    }
    if (lane == 0) { sred[wave * 2] = ep; sred[wave * 2 + 1] = en; }
    __syncthreads();
    if (tid == 0) {
        float tep = sred[0] + sred[2] + sred[4] + sred[6];
        float ten = sred[1] + sred[3] + sred[5] + sred[7];
        atomicAdd(&acc_ws[side * 2 + 0], tep);
        atomicAdd(&acc_ws[side * 2 + 1], ten);
    }
}

__global__ void mi_finalize_kernel(const int* __restrict__ len0,
                                   const int* __restrict__ len1,
                                   const float* __restrict__ acc_ws,
                                   float* __restrict__ out)
{
    const int lane = threadIdx.x;   // 1 wave
    int s0 = 0, s1 = 0;
    for (int i = lane; i < B_SENT; i += 64) {
        s0 += max(1, len0[i]);
        s1 += max(1, len1[i]);
    }
#pragma unroll
    for (int off = 32; off; off >>= 1) {
        s0 += __shfl_down(s0, off);
        s1 += __shfl_down(s1, off);
    }
    if (lane == 0) {
        const float num_nodes = (float)(s0 + s1);
        const float ep = acc_ws[0] + acc_ws[2];
        const float en = acc_ws[1] + acc_ws[3];
        out[0] = en / (num_nodes * (float)(B_SENT - 1)) - ep / num_nodes;
        out[1] = ((float)s0 + (float)s1) / (2.0f * (float)B_SENT);
    }
}

extern "C" void kernel_launch(void* const* d_in, const int* in_sizes, int n_in,
                              void* d_out, int out_size, void* d_ws, size_t ws_size,
                              hipStream_t stream) {
    const float* tok0  = (const float*)d_in[0];
    const float* tok1  = (const float*)d_in[1];
    const float* glob0 = (const float*)d_in[2];
    const float* glob1 = (const float*)d_in[3];
    const int*   len0  = (const int*)d_in[4];
    const int*   len1  = (const int*)d_in[5];
    float* out = (float*)d_out;

    float* acc    = (float*)d_ws;                       // 4 floats @ offset 0
    short* packed = (short*)((char*)d_ws + 256);        // 512 KB bf16 fragments

    hipMemsetAsync(d_ws, 0, 256, stream);
    pack_g_kernel<<<128, 256, 0, stream>>>(glob0, glob1, packed);

    dim3 grid(32768 / TM, 2);   // 1024 token-tiles x 2 sides
    mi_main_kernel<<<grid, 256, 0, stream>>>(tok0, tok1, len0, len1, packed, acc);
    mi_finalize_kernel<<<1, 64, 0, stream>>>(len0, len1, acc, out);
}